// Round 10
// baseline (342.026 us; speedup 1.0000x reference)
//
#include <hip/hip_runtime.h>
#include <stdint.h>
#include <math.h>

typedef __bf16 bf16;
typedef __bf16 bf16x8 __attribute__((ext_vector_type(8)));
typedef float  f32x4  __attribute__((ext_vector_type(4)));

#define NVALID 2080            // D*(D+1)/2 valid (h<=w) pixels
#define NCOLS  16640           // B*NVALID  (bm rows, n-dim)
#define KDIM   4096            // NS*C2D    (bm cols, k = s*128+c)

// ws layout (bytes)
#define OFF_XBT   0u           // bf16 [8][256][128] = 512 KB
#define OFF_W3B   524288u      // bf16 [512][4096] (k=s*128+c) = 4 MB
#define OFF_W2B   4718592u     // bf16 [128][512]
#define OFF_CVEC  4849664u     // f32  [128]
#define OFF_PIX   4850176u     // int  [2080]
#define OFF_W1J   4859904u     // bf16 [128][768] = 196,608 (ends 5,056,512)
#define OFF_TABW  5253120u     // f32  [2080][32][8] = 2,129,920
#define OFF_TABT  7383040u     // u8   [2080][32][8] = 532,480 (ends 7,915,520)
#define OFF_X3    8388608u     // bf16 [16640][512] = 17,039,360 (ends 25,427,968)
#define OFF_BASET 25427968u    // bf16 [8][258][256] = 1,056,768 (ends 26,484,736)
#define OFF_BM    42991616u    // bf16 [16640][4096] = 136 MB (ends 179,306,496)

__device__ __forceinline__ void gload_lds16(const void* g, void* l) {
    __builtin_amdgcn_global_load_lds(
        (const __attribute__((address_space(1))) void*)g,
        (__attribute__((address_space(3))) void*)l, 16, 0, 0);
}

// Stage 16 rows x 32 k (bf16) into LDS with XOR swizzle.
__device__ __forceinline__ void stage16(const bf16* gbase, int stride, int rbase,
                                        int k0, bf16* ldsbase, int lane) {
    int row = rbase + (lane >> 2);
    int cg  = (lane & 3) ^ ((row >> 1) & 3);
    gload_lds16(gbase + (size_t)row * stride + k0 + cg * 8, ldsbase + rbase * 32);
}

__device__ __forceinline__ bf16x8 fragld(const bf16* lds, int row, int q) {
    int c = q ^ ((row >> 1) & 3);
    return *(const bf16x8*)(lds + row * 32 + c * 8);
}

// ---------------- misc mega-kernel (absorbs k_tr) ----------------------------
// grid 1046: 0 = cvec+pix2hw; 1..16 = w2 cast; 17..528 = w3 transpose;
//            529..656 = w1 -> w1jb; 657..916 = sample table;
//            917..1045 = base transpose+cast (old k_tr, bx-917).
__global__ __launch_bounds__(256) void k_misc(const float* __restrict__ w1,
                                              const float* __restrict__ w2,
                                              const float* __restrict__ b2,
                                              const float* __restrict__ b3,
                                              const float* __restrict__ w3,
                                              const float* __restrict__ base,
                                              bf16* __restrict__ w1jb,
                                              bf16* __restrict__ w2b,
                                              bf16* __restrict__ w3b,
                                              bf16* __restrict__ baseT,
                                              float* __restrict__ cvec,
                                              int* __restrict__ pix2hw,
                                              float* __restrict__ tabw,
                                              uint8_t* __restrict__ tabt) {
    int tid = threadIdx.x, bx = blockIdx.x;
    if (bx == 0) {
        int wv = tid >> 6, ln = tid & 63;
        for (int c = wv; c < 128; c += 4) {
            const float* row = w2 + (size_t)c * 512 + ln * 8;
            float p = 0.f;
            #pragma unroll
            for (int k = 0; k < 8; k++) {
                float r = b3[ln * 8 + k]; r = r > 0.f ? r : 0.f;
                p += row[k] * r;
            }
            #pragma unroll
            for (int off = 32; off; off >>= 1) p += __shfl_down(p, off);
            if (ln == 0) {
                p += b2[c];
                cvec[c] = p > 0.f ? p : 0.f;
            }
        }
        for (int pix = tid; pix < NVALID; pix += 256) {
            int h = 0, base_ = 0;
            while (pix >= base_ + (64 - h)) { base_ += 64 - h; h++; }
            int w = h + (pix - base_);
            pix2hw[pix] = h * 64 + w;
        }
    } else if (bx <= 16) {
        int i = ((bx - 1) * 256 + tid) * 16;
        #pragma unroll
        for (int j = 0; j < 16; j++) w2b[i + j] = (bf16)w2[i + j];
    } else if (bx <= 528) {
        // transpose one o row: w3[o][c][s] -> w3b[o][s*128+c]
        __shared__ float l[128 * 33];
        int o = bx - 17;
        const float* src = w3 + (size_t)o * 4096;
        #pragma unroll
        for (int m = 0; m < 16; m++) {
            int i = m * 256 + tid;
            int c = i >> 5, s = i & 31;
            l[c * 33 + s] = src[i];
        }
        __syncthreads();
        bf16* d = w3b + (size_t)o * 4096;
        #pragma unroll
        for (int m = 0; m < 16; m++) {
            int k = m * 256 + tid;
            int s = k >> 7, c = k & 127;
            d[k] = (bf16)l[c * 33 + s];
        }
    } else if (bx <= 656) {
        // one co per block: w1[co][ci][j] -> w1jb[co][j*256+ci]
        __shared__ float l[768];
        int co = bx - 529;
        const float* src = w1 + (size_t)co * 768;
        l[tid] = src[tid]; l[tid + 256] = src[tid + 256]; l[tid + 512] = src[tid + 512];
        __syncthreads();
        bf16* d = w1jb + (size_t)co * 768;
        #pragma unroll
        for (int m = 0; m < 3; m++) {
            int k = m * 256 + tid;               // k = j*256+ci
            d[k] = (bf16)l[(k & 255) * 3 + (k >> 8)];
        }
    } else if (bx <= 916) {
        // sample table: per (pix,s) 6 (t, weight) pairs, double-exact
        int idx = (bx - 657) * 256 + tid;   // p*32+s
        if (idx >= NVALID * 32) return;
        int p = idx >> 5, s = idx & 31;
        int h = 0, base_ = 0;
        while (p >= base_ + (64 - h)) { base_ += 64 - h; h++; }
        int w = h + (p - base_);
        double sp = 4.0 * h, ep = 4.0 * (w + 1);
        double L = ep - sp + 1.0;
        double start_p = sp - L * 0.5;
        double end_p   = ep + L * 0.5;
        double step = (end_p - start_p) / 95.0;
        float*   wd = tabw + (size_t)idx * 8;
        uint8_t* td = tabt + (size_t)idx * 8;
        #pragma unroll
        for (int i = 0; i < 3; i++) {
            double pos = start_p + step * (3 * s + i);
            double tr = trunc(pos);
            double fr = pos - tr;
            int it = (int)tr;
            bool ok = (it >= 0 && it < 255);
            wd[i*2+0] = ok ? (float)((1.0 - fr) / 3.0) : 0.f;
            td[i*2+0] = (uint8_t)(ok ? it : 0);
            wd[i*2+1] = ok ? (float)(fr / 3.0) : 0.f;
            td[i*2+1] = (uint8_t)(ok ? it + 1 : 0);
        }
        wd[6] = 0.f; wd[7] = 0.f; td[6] = 0; td[7] = 0;
    } else {
        // base transpose+cast: base[b][ci][t] -> baseT[b][1+t][ci] bf16
        int id = bx - 917;
        if (id == 128) {
            for (int k = tid; k < 8 * 2 * 256; k += 256) {
                int b = k >> 9, rr = (k >> 8) & 1, ci = k & 255;
                baseT[((size_t)b * 258 + rr * 257) * 256 + ci] = (bf16)0.f;
            }
            return;
        }
        __shared__ float lt[64][65];
        int b = id >> 4, ci0 = ((id >> 2) & 3) * 64, t0 = (id & 3) * 64;
        #pragma unroll
        for (int m = 0; m < 16; m++) {
            int idx = m * 256 + tid;
            int ci_l = idx >> 6, t_l = idx & 63;
            lt[ci_l][t_l] = base[((size_t)b * 256 + ci0 + ci_l) * 256 + t0 + t_l];
        }
        __syncthreads();
        #pragma unroll
        for (int m = 0; m < 16; m++) {
            int idx = m * 256 + tid;
            int t_l = idx >> 6, ci_l = idx & 63;
            baseT[((size_t)b * 258 + 1 + t0 + t_l) * 256 + ci0 + ci_l] = (bf16)lt[ci_l][t_l];
        }
    }
}

// ---------------- conv as GEMM: xbT[b][t][co] = relu(A @ w1jb^T + b1) --------
// A row (b,t) = baseT[b*258+t .. +2][:] = 768 contiguous bf16 (t-1..t+1 halo).
// Tile 128t x 128co, K=768 (24 iters), grid 16 (b, thalf).
__global__ __launch_bounds__(256, 2) void k_cgemm(const bf16* __restrict__ baseT,
                                                  const bf16* __restrict__ w1jb,
                                                  const float* __restrict__ b1,
                                                  bf16* __restrict__ xbT) {
    __shared__ __align__(16) char lds[34816];
    bf16* As0 = (bf16*)lds;              // [2][128][32]
    bf16* Bs0 = (bf16*)(lds + 16384);    // [2][128][32]
    bf16* T2  = (bf16*)lds;              // [128][136] epilogue

    int tid = threadIdx.x, lane = tid & 63, wave = tid >> 6;
    int m16 = lane & 15, q = lane >> 4;
    int wm = wave >> 1, wn = wave & 1;
    int id = blockIdx.x;
    int b = id >> 1, t_base = (id & 1) * 128;
    const bf16* Ag = baseT + ((size_t)b * 258 + t_base) * 256;
    const bf16* Bg = w1jb;

    f32x4 acc[4][4];
    #pragma unroll
    for (int i = 0; i < 4; i++)
        #pragma unroll
        for (int j = 0; j < 4; j++) acc[i][j] = (f32x4){0.f, 0.f, 0.f, 0.f};

    stage16(Ag, 256, wave * 32,      0, As0, lane);
    stage16(Ag, 256, wave * 32 + 16, 0, As0, lane);
    stage16(Bg, 768, wave * 32,      0, Bs0, lane);
    stage16(Bg, 768, wave * 32 + 16, 0, Bs0, lane);

    for (int ks = 0; ks < 24; ks++) {
        __syncthreads();
        if (ks < 23) {
            int k0 = (ks + 1) * 32, o = ((ks + 1) & 1) * 4096;
            stage16(Ag, 256, wave * 32,      k0, As0 + o, lane);
            stage16(Ag, 256, wave * 32 + 16, k0, As0 + o, lane);
            stage16(Bg, 768, wave * 32,      k0, Bs0 + o, lane);
            stage16(Bg, 768, wave * 32 + 16, k0, Bs0 + o, lane);
        }
        const bf16* Ac = As0 + (ks & 1) * 4096;
        const bf16* Bc = Bs0 + (ks & 1) * 4096;
        bf16x8 af[4], bfv[4];
        #pragma unroll
        for (int i = 0; i < 4; i++) af[i]  = fragld(Ac, wm * 64 + i * 16 + m16, q);
        #pragma unroll
        for (int j = 0; j < 4; j++) bfv[j] = fragld(Bc, wn * 64 + j * 16 + m16, q);
        #pragma unroll
        for (int i = 0; i < 4; i++)
            #pragma unroll
            for (int j = 0; j < 4; j++)
                acc[i][j] = __builtin_amdgcn_mfma_f32_16x16x32_bf16(af[i], bfv[j], acc[i][j], 0, 0, 0);
    }
    __syncthreads();
    float biasj[4];
    #pragma unroll
    for (int j = 0; j < 4; j++) biasj[j] = b1[wn * 64 + j * 16 + m16];
    #pragma unroll
    for (int i = 0; i < 4; i++)
        #pragma unroll
        for (int r = 0; r < 4; r++) {
            int m_l = wm * 64 + i * 16 + q * 4 + r;
            #pragma unroll
            for (int j = 0; j < 4; j++) {
                int co_l = wn * 64 + j * 16 + m16;
                float v = acc[i][j][r] + biasj[j]; v = v > 0.f ? v : 0.f;
                T2[m_l * 136 + co_l] = (bf16)v;
            }
        }
    __syncthreads();
    {
        int m_l = tid >> 1, half = (tid & 1) * 64;
        bf16* dst = xbT + (size_t)(b * 256 + t_base + m_l) * 128 + half;
        const bf16* src = T2 + m_l * 136 + half;
        #pragma unroll
        for (int m = 0; m < 8; m++)
            *(bf16x8*)(dst + m * 8) = *(const bf16x8*)(src + m * 8);
    }
}

// ---------------- bm sparse v2: vectorized 16B x-loads -----------------------
// Lane split: g = lane>>4 picks sample s = sr*4+g; l16 = lane&15 owns 8 chans.
// Per j: one uint4 (16B) load of x row t, 8 FMA. t-bytes via one uint2 load.
// Per-channel accumulation order identical to v1 (j ascending).
__global__ __launch_bounds__(256) void k_bm(const bf16* __restrict__ xbT,
                                            const float* __restrict__ tabw,
                                            const uint8_t* __restrict__ tabt,
                                            bf16* __restrict__ bm) {
    int lane = threadIdx.x & 63;
    int n = __builtin_amdgcn_readfirstlane(blockIdx.x * 4 + (threadIdx.x >> 6));
    int b = n / NVALID, p = n - b * NVALID;
    const bf16* xs = xbT + (size_t)b * 32768;
    bf16* dst = bm + (size_t)n * (size_t)KDIM;
    int l16 = lane & 15, g = lane >> 4;
    for (int sr = 0; sr < 8; sr++) {
        int s = sr * 4 + g;
        const float* wv = tabw + (size_t)(p * 32 + s) * 8;
        uint2 tt = *(const uint2*)(tabt + (size_t)(p * 32 + s) * 8);
        float a[8];
        #pragma unroll
        for (int i = 0; i < 8; i++) a[i] = 0.f;
        #pragma unroll
        for (int j = 0; j < 6; j++) {
            float w = wv[j];
            int t = (j < 4) ? (int)((tt.x >> (8 * j)) & 255u)
                            : (int)((tt.y >> (8 * (j - 4))) & 255u);
            uint4 x4 = *(const uint4*)(xs + (size_t)t * 128 + l16 * 8);
            const uint32_t* xu = (const uint32_t*)&x4;
            #pragma unroll
            for (int i = 0; i < 4; i++) {
                union { uint32_t u; float f; } lo, hi;
                lo.u = xu[i] << 16;
                hi.u = xu[i] & 0xffff0000u;
                a[2 * i]     += w * lo.f;
                a[2 * i + 1] += w * hi.f;
            }
        }
        uint32_t o[4];
        #pragma unroll
        for (int i = 0; i < 4; i++) {
            union { uint32_t u; bf16 h[2]; } pk;
            pk.h[0] = (bf16)a[2 * i]; pk.h[1] = (bf16)a[2 * i + 1];
            o[i] = pk.u;
        }
        *(uint4*)(dst + (size_t)s * 128 + l16 * 8) = *(const uint4*)o;
    }
}

// ---------------- GEMM3 + out-fill: x3[n][o] = relu(w3b @ bm^T + b3) ---------
// R9 grid (mixed-size balance + XCD-aligned decode) + 8 waves per block:
// 512 threads, 2 blocks/CU (LDS 39.4 KB) -> 16 waves/CU = 4 waves/SIMD,
// doubling latency hiding of the 2-phase barrier drain (R3's null was
// confounded by the 2-generation grid wall, now removed).
// Wave-tile 32o x 64/80n: wm = wave>>1 (o-quarter), wn = wave&1 (n-part);
// acc[2][4|5]. Staging: waves 0-3 -> A rows 0..127; waves 4-7 -> B rows
// 0..127; wave 0 adds B rows 128..143 when nf==9.
// Tiles 0..15: n=144 (nf=9); 16..127: n=128. Blocks 512..1535 fill out[].
__global__ __launch_bounds__(512, 4) void k_gemm3f(const bf16* __restrict__ w3b,
                                                   const bf16* __restrict__ bm,
                                                   const float* __restrict__ b3,
                                                   bf16* __restrict__ x3,
                                                   const float* __restrict__ cvec,
                                                   float* __restrict__ out) {
    __shared__ __align__(16) char lds[39424];
    if (blockIdx.x >= 512) {
        int bo = blockIdx.x - 512;           // b*128 + o2
        float v = cvec[bo & 127];
        float* dst = out + (size_t)bo * 4096;
        for (int hw = threadIdx.x; hw < 4096; hw += 512) {
            int h = hw >> 6, w = hw & 63;
            if (w < h) dst[hw] = v;
        }
        return;
    }
    bf16* T2 = (bf16*)lds;               // [144][136] epilogue

    int tid = threadIdx.x, lane = tid & 63, wave = tid >> 6;
    int m16 = lane & 15, q = lane >> 4;
    int wm = wave >> 1, wn = wave & 1;   // wm: o-quarter (32), wn: n-part
    int id = blockIdx.x;
    int g = id & 7, ot = (id >> 3) & 3, t8 = id >> 5;
    int tile = t8 * 8 + g;               // same-tile blocks share XCD (id%8)
    int nf = (tile < 16) ? 9 : 8;        // n-frags (16 rows each)
    int n0 = (tile < 16) ? tile * 144 : 2304 + (tile - 16) * 128;
    int o0 = ot * 128;
    const bf16* Ag = w3b + (size_t)o0 * KDIM;
    const bf16* Bg = bm + (size_t)n0 * KDIM;
    int jn = (wn == 0) ? 4 : nf - 4;     // 4 or 5 n-frags for this wave

    f32x4 acc[2][5];
    #pragma unroll
    for (int i = 0; i < 2; i++)
        #pragma unroll
        for (int j = 0; j < 5; j++) acc[i][j] = (f32x4){0.f, 0.f, 0.f, 0.f};

    auto stage_tile = [&](int kt) {
        int k0 = kt * 32;
        bf16* As = (bf16*)(lds + (kt & 1) * 8192);
        bf16* Bs = (bf16*)(lds + 16384 + (kt & 1) * 9216);
        if (wave < 4) {
            stage16(Ag, KDIM, wave * 32,      k0, As, lane);
            stage16(Ag, KDIM, wave * 32 + 16, k0, As, lane);
        } else {
            int bb = (wave - 4) * 32;
            stage16(Bg, KDIM, bb,      k0, Bs, lane);
            stage16(Bg, KDIM, bb + 16, k0, Bs, lane);
        }
        if (wave == 0 && nf == 9) stage16(Bg, KDIM, 128, k0, Bs, lane);
    };

    stage_tile(0);

    for (int ks = 0; ks < 128; ks++) {
        __syncthreads();
        if (ks < 127) stage_tile(ks + 1);
        const bf16* Ac = (const bf16*)(lds + (ks & 1) * 8192);
        const bf16* Bc = (const bf16*)(lds + 16384 + (ks & 1) * 9216);
        bf16x8 af[2], bfv[5];
        #pragma unroll
        for (int i = 0; i < 2; i++) af[i]  = fragld(Ac, wm * 32 + i * 16 + m16, q);
        #pragma unroll
        for (int j = 0; j < 4; j++) bfv[j] = fragld(Bc, wn * 64 + j * 16 + m16, q);
        #pragma unroll
        for (int i = 0; i < 2; i++)
            #pragma unroll
            for (int j = 0; j < 4; j++)
                acc[i][j] = __builtin_amdgcn_mfma_f32_16x16x32_bf16(af[i], bfv[j], acc[i][j], 0, 0, 0);
        if (jn == 5) {                       // wave-uniform branch (wn==1, nf==9)
            bfv[4] = fragld(Bc, 128 + m16, q);
            #pragma unroll
            for (int i = 0; i < 2; i++)
                acc[i][4] = __builtin_amdgcn_mfma_f32_16x16x32_bf16(af[i], bfv[4], acc[i][4], 0, 0, 0);
        }
    }
    __syncthreads();
    #pragma unroll
    for (int i = 0; i < 2; i++)
        #pragma unroll
        for (int r = 0; r < 4; r++) {
            int o_l = wm * 32 + i * 16 + q * 4 + r;
            float bias = b3[o0 + o_l];
            #pragma unroll
            for (int j = 0; j < 5; j++) {
                if (j < jn) {
                    int n_l = (j < 4) ? (wn * 64 + j * 16 + m16) : (128 + m16);
                    float v = acc[i][j][r] + bias; v = v > 0.f ? v : 0.f;
                    T2[n_l * 136 + o_l] = (bf16)v;
                }
            }
        }
    __syncthreads();
    // write nf*16 rows x 128 o: idx -> row = idx>>4, c8 = idx&15
    for (int idx = tid; idx < nf * 256; idx += 512) {
        int row = idx >> 4, c8 = idx & 15;
        bf16* dst = x3 + (size_t)(n0 + row) * 512 + o0 + c8 * 8;
        *(bf16x8*)dst = *(const bf16x8*)(T2 + row * 136 + c8 * 8);
    }
}

// ---------------- GEMM4 (fill lives in gemm3f launch) ------------------------
__global__ __launch_bounds__(256, 2) void k_gemm4(const bf16* __restrict__ w2b,
                                                  const bf16* __restrict__ x3,
                                                  const float* __restrict__ b2,
                                                  const int* __restrict__ pix2hw,
                                                  float* __restrict__ out) {
    __shared__ __align__(16) char lds[24576];
    bf16* As0 = (bf16*)lds;
    bf16* Bs0 = (bf16*)(lds + 16384);

    int tid = threadIdx.x, lane = tid & 63, wave = tid >> 6;
    int m16 = lane & 15, q = lane >> 4;
    int n0 = blockIdx.x * 64;
    const bf16* Ag = w2b;
    const bf16* Bg = x3 + (size_t)n0 * 512;

    f32x4 acc[2][4];
    #pragma unroll
    for (int i = 0; i < 2; i++)
        #pragma unroll
        for (int j = 0; j < 4; j++) acc[i][j] = (f32x4){0.f, 0.f, 0.f, 0.f};

    stage16(Ag, 512, wave * 32,      0, As0, lane);
    stage16(Ag, 512, wave * 32 + 16, 0, As0, lane);
    stage16(Bg, 512, wave * 16,      0, Bs0, lane);

    for (int ks = 0; ks < 16; ks++) {
        __syncthreads();
        if (ks < 15) {
            int k0 = (ks + 1) * 32, oA = ((ks + 1) & 1) * 4096, oB = ((ks + 1) & 1) * 2048;
            stage16(Ag, 512, wave * 32,      k0, As0 + oA, lane);
            stage16(Ag, 512, wave * 32 + 16, k0, As0 + oA, lane);
            stage16(Bg, 512, wave * 16,      k0, Bs0 + oB, lane);
        }
        const bf16* Ac = As0 + (ks & 1) * 4096;
        const bf16* Bc = Bs0 + (ks & 1) * 2048;
        bf16x8 af[2], bfv[4];
        #pragma unroll
        for (int i = 0; i < 2; i++) af[i]  = fragld(Ac, wave * 32 + i * 16 + m16, q);
        #pragma unroll
        for (int j = 0; j < 4; j++) bfv[j] = fragld(Bc, j * 16 + m16, q);
        #pragma unroll
        for (int i = 0; i < 2; i++)
            #pragma unroll
            for (int j = 0; j < 4; j++)
                acc[i][j] = __builtin_amdgcn_mfma_f32_16x16x32_bf16(af[i], bfv[j], acc[i][j], 0, 0, 0);
    }
    int barr[4], hwarr[4];
    #pragma unroll
    for (int j = 0; j < 4; j++) {
        int n = n0 + j * 16 + m16;
        int bb = n / NVALID;
        barr[j] = bb; hwarr[j] = pix2hw[n - bb * NVALID];
    }
    #pragma unroll
    for (int i = 0; i < 2; i++)
        #pragma unroll
        for (int r = 0; r < 4; r++) {
            int o2 = wave * 32 + i * 16 + q * 4 + r;
            float bias = b2[o2];
            #pragma unroll
            for (int j = 0; j < 4; j++) {
                float v = acc[i][j][r] + bias; v = v > 0.f ? v : 0.f;
                out[(size_t)barr[j] * 524288 + o2 * 4096 + hwarr[j]] = v;
            }
        }
}

extern "C" void kernel_launch(void* const* d_in, const int* in_sizes, int n_in,
                              void* d_out, int out_size, void* d_ws, size_t ws_size,
                              hipStream_t stream) {
    const float* base = (const float*)d_in[0];
    const float* w1   = (const float*)d_in[1];
    const float* b1   = (const float*)d_in[2];
    const float* w3   = (const float*)d_in[3];
    const float* b3   = (const float*)d_in[4];
    const float* w2   = (const float*)d_in[5];
    const float* b2   = (const float*)d_in[6];
    float* out = (float*)d_out;
    char* ws = (char*)d_ws;
    bf16*    xbT    = (bf16*)(ws + OFF_XBT);
    bf16*    w3b    = (bf16*)(ws + OFF_W3B);
    bf16*    w2b    = (bf16*)(ws + OFF_W2B);
    float*   cvec   = (float*)(ws + OFF_CVEC);
    int*     pix2hw = (int*)(ws + OFF_PIX);
    bf16*    w1jb   = (bf16*)(ws + OFF_W1J);
    float*   tabw   = (float*)(ws + OFF_TABW);
    uint8_t* tabt   = (uint8_t*)(ws + OFF_TABT);
    bf16*    x3     = (bf16*)(ws + OFF_X3);
    bf16*    baseT  = (bf16*)(ws + OFF_BASET);
    bf16*    bm     = (bf16*)(ws + OFF_BM);

    k_misc<<<dim3(1046), dim3(256), 0, stream>>>(w1, w2, b2, b3, w3, base,
                                                 w1jb, w2b, w3b, baseT,
                                                 cvec, pix2hw, tabw, tabt);
    k_cgemm<<<dim3(16), dim3(256), 0, stream>>>(baseT, w1jb, b1, xbT);
    k_bm<<<dim3(4160), dim3(256), 0, stream>>>(xbT, tabw, tabt, bm);
    k_gemm3f<<<dim3(1536), dim3(512), 0, stream>>>(w3b, bm, b3, x3, cvec, out);
    k_gemm4<<<dim3(260), dim3(256), 0, stream>>>(w2b, x3, b2, pix2hw, out);
}

// Round 11
// 334.783 us; speedup vs baseline: 1.0216x; 1.0216x over previous
//
#include <hip/hip_runtime.h>
#include <stdint.h>
#include <math.h>

typedef __bf16 bf16;
typedef __bf16 bf16x8 __attribute__((ext_vector_type(8)));
typedef float  f32x4  __attribute__((ext_vector_type(4)));

#define NVALID 2080            // D*(D+1)/2 valid (h<=w) pixels
#define NCOLS  16640           // B*NVALID  (bm rows, n-dim)
#define KDIM   4096            // NS*C2D    (bm cols, k = s*128+c)

// ws layout (bytes)
#define OFF_XBT   0u           // bf16 [8][256][128] = 512 KB
#define OFF_W3B   524288u      // bf16 [512][4096] (k=s*128+c) = 4 MB
#define OFF_W2B   4718592u     // bf16 [128][512]
#define OFF_CVEC  4849664u     // f32  [128]
#define OFF_PIX   4850176u     // int  [2080]
#define OFF_W1J   4859904u     // bf16 [128][768] = 196,608 (ends 5,056,512)
#define OFF_TABW  5253120u     // f32  [2080][32][8] = 2,129,920
#define OFF_TABT  7383040u     // u8   [2080][32][8] = 532,480 (ends 7,915,520)
#define OFF_X3    8388608u     // bf16 [16640][512] = 17,039,360 (ends 25,427,968)
#define OFF_BASET 25427968u    // bf16 [8][258][256] = 1,056,768 (ends 26,484,736)
#define OFF_BM    42991616u    // bf16 [16640][4096] = 136 MB (ends 179,306,496)

__device__ __forceinline__ void gload_lds16(const void* g, void* l) {
    __builtin_amdgcn_global_load_lds(
        (const __attribute__((address_space(1))) void*)g,
        (__attribute__((address_space(3))) void*)l, 16, 0, 0);
}

// Stage 16 rows x 32 k (bf16) into LDS with XOR swizzle.
__device__ __forceinline__ void stage16(const bf16* gbase, int stride, int rbase,
                                        int k0, bf16* ldsbase, int lane) {
    int row = rbase + (lane >> 2);
    int cg  = (lane & 3) ^ ((row >> 1) & 3);
    gload_lds16(gbase + (size_t)row * stride + k0 + cg * 8, ldsbase + rbase * 32);
}

__device__ __forceinline__ bf16x8 fragld(const bf16* lds, int row, int q) {
    int c = q ^ ((row >> 1) & 3);
    return *(const bf16x8*)(lds + row * 32 + c * 8);
}

// ---------------- misc mega-kernel (absorbs k_tr) ----------------------------
// grid 1046: 0 = cvec+pix2hw; 1..16 = w2 cast; 17..528 = w3 transpose;
//            529..656 = w1 -> w1jb; 657..916 = sample table;
//            917..1045 = base transpose+cast (old k_tr, bx-917).
__global__ __launch_bounds__(256) void k_misc(const float* __restrict__ w1,
                                              const float* __restrict__ w2,
                                              const float* __restrict__ b2,
                                              const float* __restrict__ b3,
                                              const float* __restrict__ w3,
                                              const float* __restrict__ base,
                                              bf16* __restrict__ w1jb,
                                              bf16* __restrict__ w2b,
                                              bf16* __restrict__ w3b,
                                              bf16* __restrict__ baseT,
                                              float* __restrict__ cvec,
                                              int* __restrict__ pix2hw,
                                              float* __restrict__ tabw,
                                              uint8_t* __restrict__ tabt) {
    int tid = threadIdx.x, bx = blockIdx.x;
    if (bx == 0) {
        int wv = tid >> 6, ln = tid & 63;
        for (int c = wv; c < 128; c += 4) {
            const float* row = w2 + (size_t)c * 512 + ln * 8;
            float p = 0.f;
            #pragma unroll
            for (int k = 0; k < 8; k++) {
                float r = b3[ln * 8 + k]; r = r > 0.f ? r : 0.f;
                p += row[k] * r;
            }
            #pragma unroll
            for (int off = 32; off; off >>= 1) p += __shfl_down(p, off);
            if (ln == 0) {
                p += b2[c];
                cvec[c] = p > 0.f ? p : 0.f;
            }
        }
        for (int pix = tid; pix < NVALID; pix += 256) {
            int h = 0, base_ = 0;
            while (pix >= base_ + (64 - h)) { base_ += 64 - h; h++; }
            int w = h + (pix - base_);
            pix2hw[pix] = h * 64 + w;
        }
    } else if (bx <= 16) {
        int i = ((bx - 1) * 256 + tid) * 16;
        #pragma unroll
        for (int j = 0; j < 16; j++) w2b[i + j] = (bf16)w2[i + j];
    } else if (bx <= 528) {
        // transpose one o row: w3[o][c][s] -> w3b[o][s*128+c]
        __shared__ float l[128 * 33];
        int o = bx - 17;
        const float* src = w3 + (size_t)o * 4096;
        #pragma unroll
        for (int m = 0; m < 16; m++) {
            int i = m * 256 + tid;
            int c = i >> 5, s = i & 31;
            l[c * 33 + s] = src[i];
        }
        __syncthreads();
        bf16* d = w3b + (size_t)o * 4096;
        #pragma unroll
        for (int m = 0; m < 16; m++) {
            int k = m * 256 + tid;
            int s = k >> 7, c = k & 127;
            d[k] = (bf16)l[c * 33 + s];
        }
    } else if (bx <= 656) {
        // one co per block: w1[co][ci][j] -> w1jb[co][j*256+ci]
        __shared__ float l[768];
        int co = bx - 529;
        const float* src = w1 + (size_t)co * 768;
        l[tid] = src[tid]; l[tid + 256] = src[tid + 256]; l[tid + 512] = src[tid + 512];
        __syncthreads();
        bf16* d = w1jb + (size_t)co * 768;
        #pragma unroll
        for (int m = 0; m < 3; m++) {
            int k = m * 256 + tid;               // k = j*256+ci
            d[k] = (bf16)l[(k & 255) * 3 + (k >> 8)];
        }
    } else if (bx <= 916) {
        // sample table: per (pix,s) 6 (t, weight) pairs, double-exact
        int idx = (bx - 657) * 256 + tid;   // p*32+s
        if (idx >= NVALID * 32) return;
        int p = idx >> 5, s = idx & 31;
        int h = 0, base_ = 0;
        while (p >= base_ + (64 - h)) { base_ += 64 - h; h++; }
        int w = h + (p - base_);
        double sp = 4.0 * h, ep = 4.0 * (w + 1);
        double L = ep - sp + 1.0;
        double start_p = sp - L * 0.5;
        double end_p   = ep + L * 0.5;
        double step = (end_p - start_p) / 95.0;
        float*   wd = tabw + (size_t)idx * 8;
        uint8_t* td = tabt + (size_t)idx * 8;
        #pragma unroll
        for (int i = 0; i < 3; i++) {
            double pos = start_p + step * (3 * s + i);
            double tr = trunc(pos);
            double fr = pos - tr;
            int it = (int)tr;
            bool ok = (it >= 0 && it < 255);
            wd[i*2+0] = ok ? (float)((1.0 - fr) / 3.0) : 0.f;
            td[i*2+0] = (uint8_t)(ok ? it : 0);
            wd[i*2+1] = ok ? (float)(fr / 3.0) : 0.f;
            td[i*2+1] = (uint8_t)(ok ? it + 1 : 0);
        }
        wd[6] = 0.f; wd[7] = 0.f; td[6] = 0; td[7] = 0;
    } else {
        // base transpose+cast: base[b][ci][t] -> baseT[b][1+t][ci] bf16
        int id = bx - 917;
        if (id == 128) {
            for (int k = tid; k < 8 * 2 * 256; k += 256) {
                int b = k >> 9, rr = (k >> 8) & 1, ci = k & 255;
                baseT[((size_t)b * 258 + rr * 257) * 256 + ci] = (bf16)0.f;
            }
            return;
        }
        __shared__ float lt[64][65];
        int b = id >> 4, ci0 = ((id >> 2) & 3) * 64, t0 = (id & 3) * 64;
        #pragma unroll
        for (int m = 0; m < 16; m++) {
            int idx = m * 256 + tid;
            int ci_l = idx >> 6, t_l = idx & 63;
            lt[ci_l][t_l] = base[((size_t)b * 256 + ci0 + ci_l) * 256 + t0 + t_l];
        }
        __syncthreads();
        #pragma unroll
        for (int m = 0; m < 16; m++) {
            int idx = m * 256 + tid;
            int t_l = idx >> 6, ci_l = idx & 63;
            baseT[((size_t)b * 258 + 1 + t0 + t_l) * 256 + ci0 + ci_l] = (bf16)lt[ci_l][t_l];
        }
    }
}

// ---------------- conv as GEMM: xbT[b][t][co] = relu(A @ w1jb^T + b1) --------
// A row (b,t) = baseT[b*258+t .. +2][:] = 768 contiguous bf16 (t-1..t+1 halo).
// Tile 128t x 128co, K=768 (24 iters), grid 16 (b, thalf).
__global__ __launch_bounds__(256, 2) void k_cgemm(const bf16* __restrict__ baseT,
                                                  const bf16* __restrict__ w1jb,
                                                  const float* __restrict__ b1,
                                                  bf16* __restrict__ xbT) {
    __shared__ __align__(16) char lds[34816];
    bf16* As0 = (bf16*)lds;              // [2][128][32]
    bf16* Bs0 = (bf16*)(lds + 16384);    // [2][128][32]
    bf16* T2  = (bf16*)lds;              // [128][136] epilogue

    int tid = threadIdx.x, lane = tid & 63, wave = tid >> 6;
    int m16 = lane & 15, q = lane >> 4;
    int wm = wave >> 1, wn = wave & 1;
    int id = blockIdx.x;
    int b = id >> 1, t_base = (id & 1) * 128;
    const bf16* Ag = baseT + ((size_t)b * 258 + t_base) * 256;
    const bf16* Bg = w1jb;

    f32x4 acc[4][4];
    #pragma unroll
    for (int i = 0; i < 4; i++)
        #pragma unroll
        for (int j = 0; j < 4; j++) acc[i][j] = (f32x4){0.f, 0.f, 0.f, 0.f};

    stage16(Ag, 256, wave * 32,      0, As0, lane);
    stage16(Ag, 256, wave * 32 + 16, 0, As0, lane);
    stage16(Bg, 768, wave * 32,      0, Bs0, lane);
    stage16(Bg, 768, wave * 32 + 16, 0, Bs0, lane);

    for (int ks = 0; ks < 24; ks++) {
        __syncthreads();
        if (ks < 23) {
            int k0 = (ks + 1) * 32, o = ((ks + 1) & 1) * 4096;
            stage16(Ag, 256, wave * 32,      k0, As0 + o, lane);
            stage16(Ag, 256, wave * 32 + 16, k0, As0 + o, lane);
            stage16(Bg, 768, wave * 32,      k0, Bs0 + o, lane);
            stage16(Bg, 768, wave * 32 + 16, k0, Bs0 + o, lane);
        }
        const bf16* Ac = As0 + (ks & 1) * 4096;
        const bf16* Bc = Bs0 + (ks & 1) * 4096;
        bf16x8 af[4], bfv[4];
        #pragma unroll
        for (int i = 0; i < 4; i++) af[i]  = fragld(Ac, wm * 64 + i * 16 + m16, q);
        #pragma unroll
        for (int j = 0; j < 4; j++) bfv[j] = fragld(Bc, wn * 64 + j * 16 + m16, q);
        #pragma unroll
        for (int i = 0; i < 4; i++)
            #pragma unroll
            for (int j = 0; j < 4; j++)
                acc[i][j] = __builtin_amdgcn_mfma_f32_16x16x32_bf16(af[i], bfv[j], acc[i][j], 0, 0, 0);
    }
    __syncthreads();
    float biasj[4];
    #pragma unroll
    for (int j = 0; j < 4; j++) biasj[j] = b1[wn * 64 + j * 16 + m16];
    #pragma unroll
    for (int i = 0; i < 4; i++)
        #pragma unroll
        for (int r = 0; r < 4; r++) {
            int m_l = wm * 64 + i * 16 + q * 4 + r;
            #pragma unroll
            for (int j = 0; j < 4; j++) {
                int co_l = wn * 64 + j * 16 + m16;
                float v = acc[i][j][r] + biasj[j]; v = v > 0.f ? v : 0.f;
                T2[m_l * 136 + co_l] = (bf16)v;
            }
        }
    __syncthreads();
    {
        int m_l = tid >> 1, half = (tid & 1) * 64;
        bf16* dst = xbT + (size_t)(b * 256 + t_base + m_l) * 128 + half;
        const bf16* src = T2 + m_l * 136 + half;
        #pragma unroll
        for (int m = 0; m < 8; m++)
            *(bf16x8*)(dst + m * 8) = *(const bf16x8*)(src + m * 8);
    }
}

// ---------------- bm sparse v3: preloaded tables + full sr unroll ------------
// v2 lane split kept: g = lane>>4 picks sample s = sr*4+g; l16 = lane&15 owns
// 8 chans. v3: all 8 (tt, wv) table entries loaded into registers FIRST, then
// the 8 sr bodies fully unrolled -> all 48 xbT gathers get issued with full
// MLP instead of 8 serial ~500-cyc chains. Accumulation order per (n,s)
// identical to v2 (j ascending) -> bit-identical output.
__global__ __launch_bounds__(256) void k_bm(const bf16* __restrict__ xbT,
                                            const float* __restrict__ tabw,
                                            const uint8_t* __restrict__ tabt,
                                            bf16* __restrict__ bm) {
    int lane = threadIdx.x & 63;
    int n = __builtin_amdgcn_readfirstlane(blockIdx.x * 4 + (threadIdx.x >> 6));
    int b = n / NVALID, p = n - b * NVALID;
    const bf16* xs = xbT + (size_t)b * 32768;
    bf16* dst = bm + (size_t)n * (size_t)KDIM;
    int l16 = lane & 15, g = lane >> 4;

    uint2 tt[8];
    float wv[8][6];
    #pragma unroll
    for (int sr = 0; sr < 8; sr++) {
        int s = sr * 4 + g;
        tt[sr] = *(const uint2*)(tabt + (size_t)(p * 32 + s) * 8);
        const float* w = tabw + (size_t)(p * 32 + s) * 8;
        #pragma unroll
        for (int j = 0; j < 6; j++) wv[sr][j] = w[j];
    }
    #pragma unroll
    for (int sr = 0; sr < 8; sr++) {
        int s = sr * 4 + g;
        float a[8];
        #pragma unroll
        for (int i = 0; i < 8; i++) a[i] = 0.f;
        #pragma unroll
        for (int j = 0; j < 6; j++) {
            float w = wv[sr][j];
            int t = (j < 4) ? (int)((tt[sr].x >> (8 * j)) & 255u)
                            : (int)((tt[sr].y >> (8 * (j - 4))) & 255u);
            uint4 x4 = *(const uint4*)(xs + (size_t)t * 128 + l16 * 8);
            const uint32_t* xu = (const uint32_t*)&x4;
            #pragma unroll
            for (int i = 0; i < 4; i++) {
                union { uint32_t u; float f; } lo, hi;
                lo.u = xu[i] << 16;
                hi.u = xu[i] & 0xffff0000u;
                a[2 * i]     += w * lo.f;
                a[2 * i + 1] += w * hi.f;
            }
        }
        uint32_t o[4];
        #pragma unroll
        for (int i = 0; i < 4; i++) {
            union { uint32_t u; bf16 h[2]; } pk;
            pk.h[0] = (bf16)a[2 * i]; pk.h[1] = (bf16)a[2 * i + 1];
            o[i] = pk.u;
        }
        *(uint4*)(dst + (size_t)s * 128 + l16 * 8) = *(const uint4*)o;
    }
}

// ---------------- GEMM3 + out-fill: x3[n][o] = relu(w3b @ bm^T + b3) ---------
// R9-proven: mixed-size balance + XCD-aligned decode, 4 waves, acc[4][5],
// BK=32, 2-phase __syncthreads dbuf (all pipeline/wave variants tested
// R1/R2/R3/R6/R10: null-to-negative -> this is the structure's plateau).
// g=id&7, ot=(id>>3)&3, tile=(id>>5)*8+g -> same-tile blocks share XCD (id%8)
// -> shared L2 for the bm panel (FETCH 83 MB vs 278 MB with naive decode).
// Tiles 0..15: n=144 (nf=9); 16..127: n=128. Busiest CU = 17 units (1.046x).
// Blocks 512..1535 fill out[] lower triangle (cvec only) as backfill.
// LDS: A dbuf [0,16K), B dbuf [16K,34.8K) (slot 9216 = 144 rows); T2 aliases.
__global__ __launch_bounds__(256, 2) void k_gemm3f(const bf16* __restrict__ w3b,
                                                   const bf16* __restrict__ bm,
                                                   const float* __restrict__ b3,
                                                   bf16* __restrict__ x3,
                                                   const float* __restrict__ cvec,
                                                   float* __restrict__ out) {
    __shared__ __align__(16) char lds[39424];
    if (blockIdx.x >= 512) {
        int bo = blockIdx.x - 512;           // b*128 + o2
        float v = cvec[bo & 127];
        float* dst = out + (size_t)bo * 4096;
        for (int hw = threadIdx.x; hw < 4096; hw += 256) {
            int h = hw >> 6, w = hw & 63;
            if (w < h) dst[hw] = v;
        }
        return;
    }
    bf16* T2 = (bf16*)lds;               // [144][136] epilogue

    int tid = threadIdx.x, lane = tid & 63, wave = tid >> 6;
    int m16 = lane & 15, q = lane >> 4;
    int wm = wave >> 1, wn = wave & 1;   // wm: o-half (64), wn: n-part
    int id = blockIdx.x;
    int g = id & 7, ot = (id >> 3) & 3, t8 = id >> 5;
    int tile = t8 * 8 + g;               // same-tile blocks share XCD (id%8)
    int nf = (tile < 16) ? 9 : 8;        // n-frags (16 rows each)
    int n0 = (tile < 16) ? tile * 144 : 2304 + (tile - 16) * 128;
    int o0 = ot * 128;
    const bf16* Ag = w3b + (size_t)o0 * KDIM;
    const bf16* Bg = bm + (size_t)n0 * KDIM;
    int jn = (wn == 0) ? 4 : nf - 4;     // 4 or 5 n-frags for this wave

    f32x4 acc[4][5];
    #pragma unroll
    for (int i = 0; i < 4; i++)
        #pragma unroll
        for (int j = 0; j < 5; j++) acc[i][j] = (f32x4){0.f, 0.f, 0.f, 0.f};

    auto stage_tile = [&](int kt) {
        int k0 = kt * 32;
        bf16* As = (bf16*)(lds + (kt & 1) * 8192);
        bf16* Bs = (bf16*)(lds + 16384 + (kt & 1) * 9216);
        stage16(Ag, KDIM, wave * 32,      k0, As, lane);
        stage16(Ag, KDIM, wave * 32 + 16, k0, As, lane);
        stage16(Bg, KDIM, wave * 32,      k0, Bs, lane);
        stage16(Bg, KDIM, wave * 32 + 16, k0, Bs, lane);
        if (wave == 0 && nf == 9) stage16(Bg, KDIM, 128, k0, Bs, lane);
    };

    stage_tile(0);

    for (int ks = 0; ks < 128; ks++) {
        __syncthreads();
        if (ks < 127) stage_tile(ks + 1);
        const bf16* Ac = (const bf16*)(lds + (ks & 1) * 8192);
        const bf16* Bc = (const bf16*)(lds + 16384 + (ks & 1) * 9216);
        bf16x8 af[4], bfv[5];
        #pragma unroll
        for (int i = 0; i < 4; i++) af[i]  = fragld(Ac, wm * 64 + i * 16 + m16, q);
        #pragma unroll
        for (int j = 0; j < 4; j++) bfv[j] = fragld(Bc, wn * 64 + j * 16 + m16, q);
        #pragma unroll
        for (int i = 0; i < 4; i++)
            #pragma unroll
            for (int j = 0; j < 4; j++)
                acc[i][j] = __builtin_amdgcn_mfma_f32_16x16x32_bf16(af[i], bfv[j], acc[i][j], 0, 0, 0);
        if (jn == 5) {                       // wave-uniform branch
            bfv[4] = fragld(Bc, 128 + m16, q);
            #pragma unroll
            for (int i = 0; i < 4; i++)
                acc[i][4] = __builtin_amdgcn_mfma_f32_16x16x32_bf16(af[i], bfv[4], acc[i][4], 0, 0, 0);
        }
    }
    __syncthreads();
    #pragma unroll
    for (int i = 0; i < 4; i++)
        #pragma unroll
        for (int r = 0; r < 4; r++) {
            int o_l = wm * 64 + i * 16 + q * 4 + r;
            float bias = b3[o0 + o_l];
            #pragma unroll
            for (int j = 0; j < 5; j++) {
                if (j < jn) {
                    int n_l = (j < 4) ? (wn * 64 + j * 16 + m16) : (128 + m16);
                    float v = acc[i][j][r] + bias; v = v > 0.f ? v : 0.f;
                    T2[n_l * 136 + o_l] = (bf16)v;
                }
            }
        }
    __syncthreads();
    // write nf*16 rows x 128 o: idx = m*256+tid; row = idx>>4, c8 = idx&15
    for (int m = 0; m < nf; m++) {
        int idx = m * 256 + tid;
        int row = idx >> 4, c8 = idx & 15;
        bf16* dst = x3 + (size_t)(n0 + row) * 512 + o0 + c8 * 8;
        *(bf16x8*)dst = *(const bf16x8*)(T2 + row * 136 + c8 * 8);
    }
}

// ---------------- GEMM4 (fill lives in gemm3f launch) ------------------------
__global__ __launch_bounds__(256, 2) void k_gemm4(const bf16* __restrict__ w2b,
                                                  const bf16* __restrict__ x3,
                                                  const float* __restrict__ b2,
                                                  const int* __restrict__ pix2hw,
                                                  float* __restrict__ out) {
    __shared__ __align__(16) char lds[24576];
    bf16* As0 = (bf16*)lds;
    bf16* Bs0 = (bf16*)(lds + 16384);

    int tid = threadIdx.x, lane = tid & 63, wave = tid >> 6;
    int m16 = lane & 15, q = lane >> 4;
    int n0 = blockIdx.x * 64;
    const bf16* Ag = w2b;
    const bf16* Bg = x3 + (size_t)n0 * 512;

    f32x4 acc[2][4];
    #pragma unroll
    for (int i = 0; i < 2; i++)
        #pragma unroll
        for (int j = 0; j < 4; j++) acc[i][j] = (f32x4){0.f, 0.f, 0.f, 0.f};

    stage16(Ag, 512, wave * 32,      0, As0, lane);
    stage16(Ag, 512, wave * 32 + 16, 0, As0, lane);
    stage16(Bg, 512, wave * 16,      0, Bs0, lane);

    for (int ks = 0; ks < 16; ks++) {
        __syncthreads();
        if (ks < 15) {
            int k0 = (ks + 1) * 32, oA = ((ks + 1) & 1) * 4096, oB = ((ks + 1) & 1) * 2048;
            stage16(Ag, 512, wave * 32,      k0, As0 + oA, lane);
            stage16(Ag, 512, wave * 32 + 16, k0, As0 + oA, lane);
            stage16(Bg, 512, wave * 16,      k0, Bs0 + oB, lane);
        }
        const bf16* Ac = As0 + (ks & 1) * 4096;
        const bf16* Bc = Bs0 + (ks & 1) * 2048;
        bf16x8 af[2], bfv[4];
        #pragma unroll
        for (int i = 0; i < 2; i++) af[i]  = fragld(Ac, wave * 32 + i * 16 + m16, q);
        #pragma unroll
        for (int j = 0; j < 4; j++) bfv[j] = fragld(Bc, j * 16 + m16, q);
        #pragma unroll
        for (int i = 0; i < 2; i++)
            #pragma unroll
            for (int j = 0; j < 4; j++)
                acc[i][j] = __builtin_amdgcn_mfma_f32_16x16x32_bf16(af[i], bfv[j], acc[i][j], 0, 0, 0);
    }
    int barr[4], hwarr[4];
    #pragma unroll
    for (int j = 0; j < 4; j++) {
        int n = n0 + j * 16 + m16;
        int bb = n / NVALID;
        barr[j] = bb; hwarr[j] = pix2hw[n - bb * NVALID];
    }
    #pragma unroll
    for (int i = 0; i < 2; i++)
        #pragma unroll
        for (int r = 0; r < 4; r++) {
            int o2 = wave * 32 + i * 16 + q * 4 + r;
            float bias = b2[o2];
            #pragma unroll
            for (int j = 0; j < 4; j++) {
                float v = acc[i][j][r] + bias; v = v > 0.f ? v : 0.f;
                out[(size_t)barr[j] * 524288 + o2 * 4096 + hwarr[j]] = v;
            }
        }
}

extern "C" void kernel_launch(void* const* d_in, const int* in_sizes, int n_in,
                              void* d_out, int out_size, void* d_ws, size_t ws_size,
                              hipStream_t stream) {
    const float* base = (const float*)d_in[0];
    const float* w1   = (const float*)d_in[1];
    const float* b1   = (const float*)d_in[2];
    const float* w3   = (const float*)d_in[3];
    const float* b3   = (const float*)d_in[4];
    const float* w2   = (const float*)d_in[5];
    const float* b2   = (const float*)d_in[6];
    float* out = (float*)d_out;
    char* ws = (char*)d_ws;
    bf16*    xbT    = (bf16*)(ws + OFF_XBT);
    bf16*    w3b    = (bf16*)(ws + OFF_W3B);
    bf16*    w2b    = (bf16*)(ws + OFF_W2B);
    float*   cvec   = (float*)(ws + OFF_CVEC);
    int*     pix2hw = (int*)(ws + OFF_PIX);
    bf16*    w1jb   = (bf16*)(ws + OFF_W1J);
    float*   tabw   = (float*)(ws + OFF_TABW);
    uint8_t* tabt   = (uint8_t*)(ws + OFF_TABT);
    bf16*    x3     = (bf16*)(ws + OFF_X3);
    bf16*    baseT  = (bf16*)(ws + OFF_BASET);
    bf16*    bm     = (bf16*)(ws + OFF_BM);

    k_misc<<<dim3(1046), dim3(256), 0, stream>>>(w1, w2, b2, b3, w3, base,
                                                 w1jb, w2b, w3b, baseT,
                                                 cvec, pix2hw, tabw, tabt);
    k_cgemm<<<dim3(16), dim3(256), 0, stream>>>(baseT, w1jb, b1, xbT);
    k_bm<<<dim3(4160), dim3(256), 0, stream>>>(xbT, tabw, tabt, bm);
    k_gemm3f<<<dim3(1536), dim3(256), 0, stream>>>(w3b, bm, b3, x3, cvec, out);
    k_gemm4<<<dim3(260), dim3(256), 0, stream>>>(w2b, x3, b2, pix2hw, out);
}